// Round 1
// baseline (95.077 us; speedup 1.0000x reference)
//
#include <hip/hip_runtime.h>

// PatchPooling: out[b,p,d] = mean over s in [fr,to) of batch[b,s,d], empty -> -1.
// B=64, S=1024, D=256, P=64 per the reference setup.
constexpr int S = 1024;
constexpr int D = 256;
constexpr int P = 64;

__global__ __launch_bounds__(64) void patch_pool_kernel(
    const float* __restrict__ batch,
    const int* __restrict__ pl,
    float* __restrict__ out) {
  const int b = blockIdx.x;
  const int p = blockIdx.y;
  const int lane = threadIdx.x;  // 0..63

  // Each lane loads one patch length for row b; wave-reduce the prefix sum up to p.
  int v = pl[b * P + lane];
  int mylen = __shfl(v, p, 64);            // length of patch p
  int masked = (lane <= p) ? v : 0;
  #pragma unroll
  for (int off = 32; off > 0; off >>= 1)
    masked += __shfl_down(masked, off, 64);
  int to = __shfl(masked, 0, 64);          // inclusive cumsum at p
  int fr = to - mylen;
  int to_c = min(to, S);
  int fr_c = min(fr, S);
  int cnt = to_c - fr_c;                   // lengths >= 0, so fr <= to

  // Lane owns 4 consecutive d's: 64 lanes * 16B = 1KB coalesced per row.
  float4* outp = (float4*)(out + ((size_t)b * P + p) * D) + lane;
  if (cnt <= 0) {
    *outp = make_float4(-1.f, -1.f, -1.f, -1.f);
    return;
  }
  const float4* src = (const float4*)(batch + (size_t)b * S * D) + lane;
  float sx = 0.f, sy = 0.f, sz = 0.f, sw = 0.f;
  for (int s = fr_c; s < to_c; ++s) {
    float4 x = src[(size_t)s * (D / 4)];
    sx += x.x; sy += x.y; sz += x.z; sw += x.w;
  }
  float inv = 1.0f / (float)cnt;
  *outp = make_float4(sx * inv, sy * inv, sz * inv, sw * inv);
}

extern "C" void kernel_launch(void* const* d_in, const int* in_sizes, int n_in,
                              void* d_out, int out_size, void* d_ws, size_t ws_size,
                              hipStream_t stream) {
  const float* batch = (const float*)d_in[0];
  const int* pl = (const int*)d_in[1];
  float* out = (float*)d_out;
  const int B = in_sizes[1] / P;  // 64
  dim3 grid(B, P);
  hipLaunchKernelGGL(patch_pool_kernel, grid, dim3(64), 0, stream,
                     batch, pl, out);
}

// Round 2
// 89.872 us; speedup vs baseline: 1.0579x; 1.0579x over previous
//
#include <hip/hip_runtime.h>

// PatchPooling: out[b,p,d] = mean over s in [fr,to) of batch[b,s,d], empty -> -1.
// B=64, S=1024, D=256, P=64; patch_lengths in [0,16) so cnt <= 15 (wave-uniform).
constexpr int S = 1024;
constexpr int D = 256;
constexpr int P = 64;
constexpr int MAXLEN = 15;

__global__ __launch_bounds__(64) void patch_pool_kernel(
    const float* __restrict__ batch,
    const int* __restrict__ pl,
    float* __restrict__ out) {
  const int b = blockIdx.x;
  const int p = blockIdx.y;
  const int lane = threadIdx.x;  // 0..63

  // Lane loads one patch length for row b; wave prefix-reduce to get boundary.
  int v = pl[b * P + lane];
  int mylen = __shfl(v, p, 64);            // length of patch p
  int masked = (lane <= p) ? v : 0;
  #pragma unroll
  for (int off = 32; off > 0; off >>= 1)
    masked += __shfl_down(masked, off, 64);
  int to = __shfl(masked, 0, 64);          // inclusive cumsum at p
  int fr = to - mylen;
  int to_c = min(to, S);
  int fr_c = min(fr, S);
  int cnt = to_c - fr_c;                   // 0..15, wave-uniform

  float4* outp = (float4*)(out + ((size_t)b * P + p) * D) + lane;
  if (cnt <= 0) {
    *outp = make_float4(-1.f, -1.f, -1.f, -1.f);
    return;
  }

  const float4* src = (const float4*)(batch + (size_t)b * S * D) + lane;

  // Phase 1: issue all (<=15) row loads with NO consumer between them.
  // Branches are wave-uniform (cnt same across the wave), so loads stay in
  // flight and a single waitcnt lands before the accumulate phase.
  float4 r[MAXLEN];
  #pragma unroll
  for (int i = 0; i < MAXLEN; ++i) {
    r[i] = make_float4(0.f, 0.f, 0.f, 0.f);
    if (i < cnt) r[i] = src[(size_t)(fr_c + i) * (D / 4)];
  }

  // Phase 2: accumulate (tree-ish, compiler will schedule fine).
  float sx = 0.f, sy = 0.f, sz = 0.f, sw = 0.f;
  #pragma unroll
  for (int i = 0; i < MAXLEN; ++i) {
    sx += r[i].x; sy += r[i].y; sz += r[i].z; sw += r[i].w;
  }
  // Safety tail (never taken for the given input range, keeps generality).
  for (int s = fr_c + MAXLEN; s < to_c; ++s) {
    float4 x = src[(size_t)s * (D / 4)];
    sx += x.x; sy += x.y; sz += x.z; sw += x.w;
  }

  float inv = 1.0f / (float)cnt;
  *outp = make_float4(sx * inv, sy * inv, sz * inv, sw * inv);
}

extern "C" void kernel_launch(void* const* d_in, const int* in_sizes, int n_in,
                              void* d_out, int out_size, void* d_ws, size_t ws_size,
                              hipStream_t stream) {
  const float* batch = (const float*)d_in[0];
  const int* pl = (const int*)d_in[1];
  float* out = (float*)d_out;
  const int B = in_sizes[1] / P;  // 64
  dim3 grid(B, P);
  hipLaunchKernelGGL(patch_pool_kernel, grid, dim3(64), 0, stream,
                     batch, pl, out);
}